// Round 1
// baseline (783.885 us; speedup 1.0000x reference)
//
#include <hip/hip_runtime.h>
#include <math.h>

#define N_OBJ 4096
#define F     256
#define NE    8
#define EPT   131072
#define KCAT  (NE * F)      // 2048
#define C_OUT 128
#define FC1_K (N_OBJ * F)   // 1048576

// ---------------- graph preprocessing (once per launch) ----------------

__global__ __launch_bounds__(256) void k_count_deg(const int* __restrict__ edges,
                                                   int* __restrict__ deg) {
    int gid = blockIdx.x * 256 + threadIdx.x;   // NE*EPT threads
    int e = gid >> 17;                          // EPT = 2^17
    int i = gid & (EPT - 1);
    int dst = edges[(e * 2 + 1) * EPT + i];
    atomicAdd(&deg[e * N_OBJ + dst], 1);
}

__global__ __launch_bounds__(256) void k_scan(const int* __restrict__ deg,
                                              int* __restrict__ rowptr,
                                              int* __restrict__ cursor,
                                              float* __restrict__ invdeg) {
    int e = blockIdx.x;       // one block per etype
    int t = threadIdx.x;      // 256
    __shared__ int part[256];
    int local[16];
    int base = e * N_OBJ + t * 16;
    int s = 0;
#pragma unroll
    for (int i = 0; i < 16; ++i) { local[i] = deg[base + i]; s += local[i]; }
    part[t] = s;
    __syncthreads();
    for (int off = 1; off < 256; off <<= 1) {
        int v = (t >= off) ? part[t - off] : 0;
        __syncthreads();
        part[t] += v;
        __syncthreads();
    }
    int run = part[t] - s;    // exclusive prefix within etype
#pragma unroll
    for (int i = 0; i < 16; ++i) {
        rowptr[base + i] = run;
        cursor[base + i] = run;
        invdeg[base + i] = 1.0f / fmaxf((float)local[i], 1.0f);
        run += local[i];
    }
}

__global__ __launch_bounds__(256) void k_fill(const int* __restrict__ edges,
                                              int* __restrict__ cursor,
                                              int* __restrict__ col) {
    int gid = blockIdx.x * 256 + threadIdx.x;
    int e = gid >> 17;
    int i = gid & (EPT - 1);
    int src = edges[(e * 2 + 0) * EPT + i];
    int dst = edges[(e * 2 + 1) * EPT + i];
    int pos = atomicAdd(&cursor[e * N_OBJ + dst], 1);
    col[e * EPT + pos] = src;
}

// ---------------- per-layer: aggregate (mean over in-edges, per etype) ----------------
// ah[n][e*F + f] = invdeg[e][n] * sum_{edges (s->n) in e} h_in[s][f]
__global__ __launch_bounds__(64) void k_aggregate(const float* __restrict__ h_in,
                                                  const int* __restrict__ rowptr,
                                                  const int* __restrict__ deg,
                                                  const int* __restrict__ col,
                                                  const float* __restrict__ invdeg,
                                                  float* __restrict__ ah) {
    int bid = blockIdx.x;                 // NE * N_OBJ blocks
    int e = bid >> 12;                    // N_OBJ = 2^12
    int n = bid & (N_OBJ - 1);
    int lane = threadIdx.x;               // 64 lanes, each owns 4 channels (float4)
    int idx = e * N_OBJ + n;
    int beg = rowptr[idx];
    int cnt = deg[idx];
    const int* cl = col + e * EPT + beg;
    const float4* h4 = (const float4*)h_in;
    float4 acc = make_float4(0.f, 0.f, 0.f, 0.f);
    int k = 0;
    for (; k + 4 <= cnt; k += 4) {
        int s0 = cl[k], s1 = cl[k + 1], s2 = cl[k + 2], s3 = cl[k + 3];
        float4 v0 = h4[s0 * 64 + lane];
        float4 v1 = h4[s1 * 64 + lane];
        float4 v2 = h4[s2 * 64 + lane];
        float4 v3 = h4[s3 * 64 + lane];
        acc.x += v0.x + v1.x + v2.x + v3.x;
        acc.y += v0.y + v1.y + v2.y + v3.y;
        acc.z += v0.z + v1.z + v2.z + v3.z;
        acc.w += v0.w + v1.w + v2.w + v3.w;
    }
    for (; k < cnt; ++k) {
        int s0 = cl[k];
        float4 v = h4[s0 * 64 + lane];
        acc.x += v.x; acc.y += v.y; acc.z += v.z; acc.w += v.w;
    }
    float sc = invdeg[idx];
    float4 r = make_float4(acc.x * sc, acc.y * sc, acc.z * sc, acc.w * sc);
    ((float4*)ah)[n * (KCAT / 4) + e * (F / 4) + lane] = r;
}

// ---------------- per-layer GEMM: C = relu(AH x Wcat + bias_mask) ----------------
// AH: [4096][2048] row-major. B[k][j] = W[e][j][f], k = e*256+f. BK=32 never crosses e.
__global__ __launch_bounds__(256) void k_gemm_layer(const float* __restrict__ A,
                                                    const float* __restrict__ W,
                                                    const float* __restrict__ bias,
                                                    const int* __restrict__ deg,
                                                    float* __restrict__ Cout) {
    __shared__ float As[32][68];   // [k][m], padded: 68*4B = 272B = 17x16B (keeps float4 align)
    __shared__ float Bs[32][68];   // [k][j]
    int m0 = blockIdx.x * 64;
    int n0 = blockIdx.y * 64;
    int t = threadIdx.x;
    int tx = t & 15, ty = t >> 4;
    float acc[4][4] = {};
    for (int k0 = 0; k0 < KCAT; k0 += 32) {
        int e = k0 >> 8, f0 = k0 & 255;
        const float* Wp = W + e * F * F;
#pragma unroll
        for (int p = 0; p < 2; ++p) {
            int q = t + p * 256;
            int row = q >> 3, kq = q & 7;
            float4 va = *(const float4*)&A[(size_t)(m0 + row) * KCAT + k0 + kq * 4];
            As[kq * 4 + 0][row] = va.x;
            As[kq * 4 + 1][row] = va.y;
            As[kq * 4 + 2][row] = va.z;
            As[kq * 4 + 3][row] = va.w;
            float4 vb = *(const float4*)&Wp[(n0 + row) * F + f0 + kq * 4];
            Bs[kq * 4 + 0][row] = vb.x;
            Bs[kq * 4 + 1][row] = vb.y;
            Bs[kq * 4 + 2][row] = vb.z;
            Bs[kq * 4 + 3][row] = vb.w;
        }
        __syncthreads();
#pragma unroll
        for (int kk = 0; kk < 32; ++kk) {
            float4 a4 = *(const float4*)&As[kk][ty * 4];
            float4 b4 = *(const float4*)&Bs[kk][tx * 4];
            float av[4] = {a4.x, a4.y, a4.z, a4.w};
            float bv[4] = {b4.x, b4.y, b4.z, b4.w};
#pragma unroll
            for (int i2 = 0; i2 < 4; ++i2)
#pragma unroll
                for (int j2 = 0; j2 < 4; ++j2)
                    acc[i2][j2] = fmaf(av[i2], bv[j2], acc[i2][j2]);
        }
        __syncthreads();
    }
#pragma unroll
    for (int i2 = 0; i2 < 4; ++i2) {
        int m = m0 + ty * 4 + i2;
        float badd[4] = {0.f, 0.f, 0.f, 0.f};
#pragma unroll
        for (int e = 0; e < NE; ++e) {
            if (deg[e * N_OBJ + m] > 0) {
#pragma unroll
                for (int j2 = 0; j2 < 4; ++j2)
                    badd[j2] += bias[e * F + n0 + tx * 4 + j2];
            }
        }
#pragma unroll
        for (int j2 = 0; j2 < 4; ++j2) {
            float v = acc[i2][j2] + badd[j2];
            Cout[(size_t)m * F + n0 + tx * 4 + j2] = fmaxf(v, 0.0f);
        }
    }
}

// ---------------- fc1 GEMV: zpart[c][j] = dot(fc1_w[j, c-chunk], flat[c-chunk]) ----------------
__global__ __launch_bounds__(256) void k_fc1(const float* __restrict__ Wf,
                                             const float* __restrict__ flat,
                                             float* __restrict__ zpart) {
    int c = blockIdx.x;   // 16 chunks of 65536
    int j = blockIdx.y;   // 256 rows
    int t = threadIdx.x;
    const float4* wp = (const float4*)(Wf + (size_t)j * FC1_K + (size_t)c * 65536);
    const float4* fp = (const float4*)(flat + (size_t)c * 65536);
    float s = 0.0f;
#pragma unroll 4
    for (int it = 0; it < 64; ++it) {
        int q = it * 256 + t;
        float4 w4 = wp[q];
        float4 x4 = fp[q];
        s = fmaf(w4.x, x4.x, s);
        s = fmaf(w4.y, x4.y, s);
        s = fmaf(w4.z, x4.z, s);
        s = fmaf(w4.w, x4.w, s);
    }
#pragma unroll
    for (int off = 32; off > 0; off >>= 1) s += __shfl_down(s, off, 64);
    __shared__ float red[4];
    if ((t & 63) == 0) red[t >> 6] = s;
    __syncthreads();
    if (t == 0) zpart[c * 256 + j] = red[0] + red[1] + red[2] + red[3];
}

// ---------------- finish: z = relu(sum zpart + b1); out = sigmoid(fc2_w z + fc2_b) ------------
__global__ __launch_bounds__(256) void k_final(const float* __restrict__ zpart,
                                               const float* __restrict__ fc1_b,
                                               const float* __restrict__ fc2_w,
                                               const float* __restrict__ fc2_b,
                                               float* __restrict__ out) {
    __shared__ float z[256];
    int t = threadIdx.x;
    float s = fc1_b[t];
#pragma unroll
    for (int c = 0; c < 16; ++c) s += zpart[c * 256 + t];
    z[t] = fmaxf(s, 0.0f);
    __syncthreads();
    if (t < C_OUT) {
        float acc = fc2_b[t];
        for (int k = 0; k < 256; ++k) acc = fmaf(fc2_w[t * 256 + k], z[k], acc);
        out[t] = 1.0f / (1.0f + expf(-acc));
    }
}

extern "C" void kernel_launch(void* const* d_in, const int* in_sizes, int n_in,
                              void* d_out, int out_size, void* d_ws, size_t ws_size,
                              hipStream_t stream) {
    const float* feat  = (const float*)d_in[0];
    const int*   edges = (const int*)d_in[1];
    const float* W0    = (const float*)d_in[2];
    const float* b0    = (const float*)d_in[3];
    const float* W1    = (const float*)d_in[4];
    const float* b1    = (const float*)d_in[5];
    const float* W2    = (const float*)d_in[6];
    const float* b2    = (const float*)d_in[7];
    const float* fc1_w = (const float*)d_in[8];
    const float* fc1_b = (const float*)d_in[9];
    const float* fc2_w = (const float*)d_in[10];
    const float* fc2_b = (const float*)d_in[11];
    float* out = (float*)d_out;

    char* ws = (char*)d_ws;
    size_t off = 0;
    auto alloc = [&](size_t bytes) {
        void* p = ws + off;
        off = (off + bytes + 255) & ~(size_t)255;
        return p;
    };
    int*   deg    = (int*)  alloc(NE * N_OBJ * 4);
    int*   rowptr = (int*)  alloc(NE * N_OBJ * 4);
    int*   cursor = (int*)  alloc(NE * N_OBJ * 4);
    float* invdeg = (float*)alloc(NE * N_OBJ * 4);
    int*   col    = (int*)  alloc(NE * EPT * 4);
    float* zpart  = (float*)alloc(16 * 256 * 4);
    float* h_a    = (float*)alloc((size_t)N_OBJ * F * 4);
    float* h_b    = (float*)alloc((size_t)N_OBJ * F * 4);
    float* ah     = (float*)alloc((size_t)N_OBJ * KCAT * 4);
    (void)ws_size; (void)in_sizes; (void)n_in; (void)out_size;

    hipMemsetAsync(deg, 0, NE * N_OBJ * 4, stream);
    k_count_deg<<<NE * EPT / 256, 256, 0, stream>>>(edges, deg);
    k_scan<<<NE, 256, 0, stream>>>(deg, rowptr, cursor, invdeg);
    k_fill<<<NE * EPT / 256, 256, 0, stream>>>(edges, cursor, col);

    dim3 ggrid(N_OBJ / 64, F / 64);

    // layer 0
    k_aggregate<<<NE * N_OBJ, 64, 0, stream>>>(feat, rowptr, deg, col, invdeg, ah);
    k_gemm_layer<<<ggrid, 256, 0, stream>>>(ah, W0, b0, deg, h_a);
    // layer 1
    k_aggregate<<<NE * N_OBJ, 64, 0, stream>>>(h_a, rowptr, deg, col, invdeg, ah);
    k_gemm_layer<<<ggrid, 256, 0, stream>>>(ah, W1, b1, deg, h_b);
    // layer 2
    k_aggregate<<<NE * N_OBJ, 64, 0, stream>>>(h_b, rowptr, deg, col, invdeg, ah);
    k_gemm_layer<<<ggrid, 256, 0, stream>>>(ah, W2, b2, deg, h_a);

    dim3 fgrid(16, 256);
    k_fc1<<<fgrid, 256, 0, stream>>>(fc1_w, h_a, zpart);
    k_final<<<1, 256, 0, stream>>>(zpart, fc1_b, fc2_w, fc2_b, out);
}

// Round 2
// 500.964 us; speedup vs baseline: 1.5648x; 1.5648x over previous
//
#include <hip/hip_runtime.h>
#include <math.h>

#define N_OBJ 4096
#define F     256
#define NE    8
#define EPT   131072
#define KCAT  (NE * F)      // 2048
#define C_OUT 128
#define FC1_K (N_OBJ * F)   // 1048576

typedef __attribute__((ext_vector_type(8))) short s8v;   // 8 bf16 (4 VGPRs) MFMA operand
typedef __attribute__((ext_vector_type(4))) float f4v;   // 4 f32 accumulator

__device__ inline float bf2f(unsigned short u) {
    unsigned int x = ((unsigned int)u) << 16;
    return __builtin_bit_cast(float, x);
}
__device__ inline unsigned short f2bf(float f) {
    unsigned int x = __builtin_bit_cast(unsigned int, f);
    x += 0x7fff + ((x >> 16) & 1);   // RNE
    return (unsigned short)(x >> 16);
}

// ---------------- graph preprocessing (once per launch) ----------------

__global__ __launch_bounds__(256) void k_count_deg(const int* __restrict__ edges,
                                                   int* __restrict__ deg) {
    int gid = blockIdx.x * 256 + threadIdx.x;   // NE*EPT threads
    int e = gid >> 17;                          // EPT = 2^17
    int i = gid & (EPT - 1);
    int dst = edges[(e * 2 + 1) * EPT + i];
    atomicAdd(&deg[e * N_OBJ + dst], 1);
}

__global__ __launch_bounds__(256) void k_scan(const int* __restrict__ deg,
                                              int* __restrict__ rowptr,
                                              int* __restrict__ cursor,
                                              float* __restrict__ invdeg) {
    int e = blockIdx.x;
    int t = threadIdx.x;
    __shared__ int part[256];
    int local[16];
    int base = e * N_OBJ + t * 16;
    int s = 0;
#pragma unroll
    for (int i = 0; i < 16; ++i) { local[i] = deg[base + i]; s += local[i]; }
    part[t] = s;
    __syncthreads();
    for (int off = 1; off < 256; off <<= 1) {
        int v = (t >= off) ? part[t - off] : 0;
        __syncthreads();
        part[t] += v;
        __syncthreads();
    }
    int run = part[t] - s;
#pragma unroll
    for (int i = 0; i < 16; ++i) {
        rowptr[base + i] = run;
        cursor[base + i] = run;
        invdeg[base + i] = 1.0f / fmaxf((float)local[i], 1.0f);
        run += local[i];
    }
}

__global__ __launch_bounds__(256) void k_fill(const int* __restrict__ edges,
                                              int* __restrict__ cursor,
                                              int* __restrict__ col) {
    int gid = blockIdx.x * 256 + threadIdx.x;
    int e = gid >> 17;
    int i = gid & (EPT - 1);
    int src = edges[(e * 2 + 0) * EPT + i];
    int dst = edges[(e * 2 + 1) * EPT + i];
    int pos = atomicAdd(&cursor[e * N_OBJ + dst], 1);
    col[e * EPT + pos] = src;
}

__global__ __launch_bounds__(256) void k_bmask(const int* __restrict__ deg,
                                               unsigned int* __restrict__ bmask) {
    int n = blockIdx.x * 256 + threadIdx.x;
    unsigned int m = 0;
#pragma unroll
    for (int e = 0; e < NE; ++e) m |= (deg[e * N_OBJ + n] > 0) ? (1u << e) : 0u;
    bmask[n] = m;
}

// fp32 -> bf16 weight conversion (n4 float4 elements)
__global__ __launch_bounds__(256) void k_cvt(const float* __restrict__ s,
                                             unsigned short* __restrict__ d, int n4) {
    int i = blockIdx.x * 256 + threadIdx.x;
    if (i < n4) {
        float4 v = ((const float4*)s)[i];
        ushort4 o;
        o.x = f2bf(v.x); o.y = f2bf(v.y); o.z = f2bf(v.z); o.w = f2bf(v.w);
        ((ushort4*)d)[i] = o;
    }
}

// ---------------- per-layer: aggregate (mean over in-edges, per etype) ----------------
// ah[n][e*F + f] = invdeg[e][n] * sum h_in[src][f]   (bf16 output)
template <int INBF>
__global__ __launch_bounds__(64) void k_aggregate(const void* __restrict__ h_in,
                                                  const int* __restrict__ rowptr,
                                                  const int* __restrict__ deg,
                                                  const int* __restrict__ col,
                                                  const float* __restrict__ invdeg,
                                                  unsigned short* __restrict__ ah) {
    int bid = blockIdx.x;
    int e = bid >> 12;
    int n = bid & (N_OBJ - 1);
    int lane = threadIdx.x;               // 64 lanes × 4 channels
    int idx = e * N_OBJ + n;
    int beg = rowptr[idx];
    int cnt = deg[idx];
    const int* cl = col + e * EPT + beg;
    float a0 = 0.f, a1 = 0.f, a2 = 0.f, a3 = 0.f;
    int k = 0;
    if (INBF) {
        const ushort4* h4 = (const ushort4*)h_in;
        for (; k + 4 <= cnt; k += 4) {
            int s0 = cl[k], s1 = cl[k + 1], s2 = cl[k + 2], s3 = cl[k + 3];
            ushort4 v0 = h4[s0 * 64 + lane];
            ushort4 v1 = h4[s1 * 64 + lane];
            ushort4 v2 = h4[s2 * 64 + lane];
            ushort4 v3 = h4[s3 * 64 + lane];
            a0 += bf2f(v0.x) + bf2f(v1.x) + bf2f(v2.x) + bf2f(v3.x);
            a1 += bf2f(v0.y) + bf2f(v1.y) + bf2f(v2.y) + bf2f(v3.y);
            a2 += bf2f(v0.z) + bf2f(v1.z) + bf2f(v2.z) + bf2f(v3.z);
            a3 += bf2f(v0.w) + bf2f(v1.w) + bf2f(v2.w) + bf2f(v3.w);
        }
        for (; k < cnt; ++k) {
            ushort4 v = h4[cl[k] * 64 + lane];
            a0 += bf2f(v.x); a1 += bf2f(v.y); a2 += bf2f(v.z); a3 += bf2f(v.w);
        }
    } else {
        const float4* h4 = (const float4*)h_in;
        for (; k + 4 <= cnt; k += 4) {
            int s0 = cl[k], s1 = cl[k + 1], s2 = cl[k + 2], s3 = cl[k + 3];
            float4 v0 = h4[s0 * 64 + lane];
            float4 v1 = h4[s1 * 64 + lane];
            float4 v2 = h4[s2 * 64 + lane];
            float4 v3 = h4[s3 * 64 + lane];
            a0 += v0.x + v1.x + v2.x + v3.x;
            a1 += v0.y + v1.y + v2.y + v3.y;
            a2 += v0.z + v1.z + v2.z + v3.z;
            a3 += v0.w + v1.w + v2.w + v3.w;
        }
        for (; k < cnt; ++k) {
            float4 v = h4[cl[k] * 64 + lane];
            a0 += v.x; a1 += v.y; a2 += v.z; a3 += v.w;
        }
    }
    float sc = invdeg[idx];
    ushort4 o;
    o.x = f2bf(a0 * sc); o.y = f2bf(a1 * sc); o.z = f2bf(a2 * sc); o.w = f2bf(a3 * sc);
    ((ushort4*)ah)[n * (KCAT / 4) + e * (F / 4) + lane] = o;
}

// ---------------- per-layer GEMM (bf16 MFMA): C = relu(AH x Wcat^T + bias_mask) ----------------
// AH [4096][2048] bf16 row-major; Wb [8][256][256] bf16; tile 64x64, BK=32, 4 waves.
template <int OUTBF>
__global__ __launch_bounds__(256) void k_gemm(const unsigned short* __restrict__ A,
                                              const unsigned short* __restrict__ Wb,
                                              const float* __restrict__ bias,
                                              const unsigned int* __restrict__ bmask,
                                              void* __restrict__ Cout) {
    __shared__ short As[64][40];   // 80 B rows: 16 lanes -> 8 banks (2-way, free)
    __shared__ short Bs[64][40];
    int m0 = blockIdx.x * 64, n0 = blockIdx.y * 64;
    int t = threadIdx.x;
    int wave = t >> 6, lane = t & 63;
    int srow = t >> 2, sseg = t & 3;          // staging: thread -> (row, 16B segment)
    int r = lane & 15, g = lane >> 4;
    f4v acc[4];
#pragma unroll
    for (int i = 0; i < 4; ++i) acc[i] = (f4v){0.f, 0.f, 0.f, 0.f};
    const short* Ap = (const short*)A;
    const short* Wp = (const short*)Wb;
    for (int k0 = 0; k0 < KCAT; k0 += 32) {
        int e = k0 >> 8, f0 = k0 & 255;
        s8v va = *(const s8v*)(Ap + (size_t)(m0 + srow) * KCAT + k0 + sseg * 8);
        s8v vb = *(const s8v*)(Wp + (size_t)e * F * F + (size_t)(n0 + srow) * F + f0 + sseg * 8);
        __syncthreads();
        *(s8v*)&As[srow][sseg * 8] = va;
        *(s8v*)&Bs[srow][sseg * 8] = vb;
        __syncthreads();
        s8v bfrag = *(const s8v*)&Bs[wave * 16 + r][g * 8];
#pragma unroll
        for (int mf = 0; mf < 4; ++mf) {
            s8v afrag = *(const s8v*)&As[mf * 16 + r][g * 8];
            acc[mf] = __builtin_amdgcn_mfma_f32_16x16x32_bf16(afrag, bfrag, acc[mf], 0, 0, 0);
        }
    }
    // epilogue: C/D layout col=lane&15, row=(lane>>4)*4+reg (m89-verified)
    int coln = n0 + wave * 16 + r;
    float bcol[NE];
#pragma unroll
    for (int e = 0; e < NE; ++e) bcol[e] = bias[e * F + coln];
#pragma unroll
    for (int mf = 0; mf < 4; ++mf) {
#pragma unroll
        for (int reg = 0; reg < 4; ++reg) {
            int m = m0 + mf * 16 + g * 4 + reg;
            unsigned int msk = bmask[m];
            float v = acc[mf][reg];
#pragma unroll
            for (int e = 0; e < NE; ++e)
                if ((msk >> e) & 1) v += bcol[e];
            v = fmaxf(v, 0.f);
            if (OUTBF) ((unsigned short*)Cout)[(size_t)m * F + coln] = f2bf(v);
            else       ((float*)Cout)[(size_t)m * F + coln] = v;
        }
    }
}

// ---------------- fc1 GEMV: zpart[c][j] = dot(fc1_w[j, chunk c], flat[chunk c]) ----------------
__global__ __launch_bounds__(256) void k_fc1(const float* __restrict__ Wf,
                                             const float* __restrict__ flat,
                                             float* __restrict__ zpart) {
    int c = blockIdx.x;   // 16 chunks of 65536
    int j = blockIdx.y;   // 256 rows
    int t = threadIdx.x;
    const float4* wp = (const float4*)(Wf + (size_t)j * FC1_K + (size_t)c * 65536);
    const float4* fp = (const float4*)(flat + (size_t)c * 65536);
    float s = 0.0f;
#pragma unroll 4
    for (int it = 0; it < 64; ++it) {
        int q = it * 256 + t;
        float4 w4 = wp[q];
        float4 x4 = fp[q];
        s = fmaf(w4.x, x4.x, s);
        s = fmaf(w4.y, x4.y, s);
        s = fmaf(w4.z, x4.z, s);
        s = fmaf(w4.w, x4.w, s);
    }
#pragma unroll
    for (int off = 32; off > 0; off >>= 1) s += __shfl_down(s, off, 64);
    __shared__ float red[4];
    if ((t & 63) == 0) red[t >> 6] = s;
    __syncthreads();
    if (t == 0) zpart[c * 256 + j] = red[0] + red[1] + red[2] + red[3];
}

__global__ __launch_bounds__(256) void k_final(const float* __restrict__ zpart,
                                               const float* __restrict__ fc1_b,
                                               const float* __restrict__ fc2_w,
                                               const float* __restrict__ fc2_b,
                                               float* __restrict__ out) {
    __shared__ float z[256];
    int t = threadIdx.x;
    float s = fc1_b[t];
#pragma unroll
    for (int c = 0; c < 16; ++c) s += zpart[c * 256 + t];
    z[t] = fmaxf(s, 0.0f);
    __syncthreads();
    if (t < C_OUT) {
        float acc = fc2_b[t];
        for (int k = 0; k < 256; ++k) acc = fmaf(fc2_w[t * 256 + k], z[k], acc);
        out[t] = 1.0f / (1.0f + expf(-acc));
    }
}

extern "C" void kernel_launch(void* const* d_in, const int* in_sizes, int n_in,
                              void* d_out, int out_size, void* d_ws, size_t ws_size,
                              hipStream_t stream) {
    const float* feat  = (const float*)d_in[0];
    const int*   edges = (const int*)d_in[1];
    const float* W0    = (const float*)d_in[2];
    const float* b0    = (const float*)d_in[3];
    const float* W1    = (const float*)d_in[4];
    const float* b1    = (const float*)d_in[5];
    const float* W2    = (const float*)d_in[6];
    const float* b2    = (const float*)d_in[7];
    const float* fc1_w = (const float*)d_in[8];
    const float* fc1_b = (const float*)d_in[9];
    const float* fc2_w = (const float*)d_in[10];
    const float* fc2_b = (const float*)d_in[11];
    float* out = (float*)d_out;

    char* ws = (char*)d_ws;
    size_t off = 0;
    auto alloc = [&](size_t bytes) {
        void* p = ws + off;
        off = (off + bytes + 255) & ~(size_t)255;
        return p;
    };
    int*            deg    = (int*)            alloc(NE * N_OBJ * 4);
    int*            rowptr = (int*)            alloc(NE * N_OBJ * 4);
    int*            cursor = (int*)            alloc(NE * N_OBJ * 4);
    float*          invdeg = (float*)          alloc(NE * N_OBJ * 4);
    int*            col    = (int*)            alloc(NE * EPT * 4);
    unsigned int*   bmask  = (unsigned int*)   alloc(N_OBJ * 4);
    float*          zpart  = (float*)          alloc(16 * 256 * 4);
    unsigned short* Wb0    = (unsigned short*) alloc((size_t)NE * F * F * 2);
    unsigned short* Wb1    = (unsigned short*) alloc((size_t)NE * F * F * 2);
    unsigned short* Wb2    = (unsigned short*) alloc((size_t)NE * F * F * 2);
    unsigned short* h_ba   = (unsigned short*) alloc((size_t)N_OBJ * F * 2);
    unsigned short* h_bb   = (unsigned short*) alloc((size_t)N_OBJ * F * 2);
    float*          h_f32  = (float*)          alloc((size_t)N_OBJ * F * 4);
    unsigned short* ah     = (unsigned short*) alloc((size_t)N_OBJ * KCAT * 2);
    (void)ws_size; (void)in_sizes; (void)n_in; (void)out_size;

    hipMemsetAsync(deg, 0, NE * N_OBJ * 4, stream);
    k_count_deg<<<NE * EPT / 256, 256, 0, stream>>>(edges, deg);
    k_scan<<<NE, 256, 0, stream>>>(deg, rowptr, cursor, invdeg);
    k_fill<<<NE * EPT / 256, 256, 0, stream>>>(edges, cursor, col);
    k_bmask<<<N_OBJ / 256, 256, 0, stream>>>(deg, bmask);
    k_cvt<<<512, 256, 0, stream>>>(W0, Wb0, NE * F * F / 4);
    k_cvt<<<512, 256, 0, stream>>>(W1, Wb1, NE * F * F / 4);
    k_cvt<<<512, 256, 0, stream>>>(W2, Wb2, NE * F * F / 4);

    dim3 ggrid(N_OBJ / 64, F / 64);

    // layer 0 (fp32 feat in, bf16 h out)
    k_aggregate<0><<<NE * N_OBJ, 64, 0, stream>>>(feat, rowptr, deg, col, invdeg, ah);
    k_gemm<1><<<ggrid, 256, 0, stream>>>(ah, Wb0, b0, bmask, h_ba);
    // layer 1 (bf16 in, bf16 out)
    k_aggregate<1><<<NE * N_OBJ, 64, 0, stream>>>(h_ba, rowptr, deg, col, invdeg, ah);
    k_gemm<1><<<ggrid, 256, 0, stream>>>(ah, Wb1, b1, bmask, h_bb);
    // layer 2 (bf16 in, fp32 out for fc1)
    k_aggregate<1><<<NE * N_OBJ, 64, 0, stream>>>(h_bb, rowptr, deg, col, invdeg, ah);
    k_gemm<0><<<ggrid, 256, 0, stream>>>(ah, Wb2, b2, bmask, h_f32);

    dim3 fgrid(16, 256);
    k_fc1<<<fgrid, 256, 0, stream>>>(fc1_w, h_f32, zpart);
    k_final<<<1, 256, 0, stream>>>(zpart, fc1_b, fc2_w, fc2_b, out);
}